// Round 4
// baseline (134.243 us; speedup 1.0000x reference)
//
#include <hip/hip_runtime.h>
#include <hip/hip_bf16.h>

// out[bw][m][c] = sum_n posmap[m][n][c%4] * x[bw][n][c] + bias[m]
// pos_score depends only on d=n-m  =>  for interior m (8..247) the softmax
// weights are THE SAME 17-tap stencil (per s). This is a depthwise 17-tap
// 1-D conv with constant weights + 16 renormalized edge rows.
//
// R4: no LDS at all. 68 interior weights live in SGPRs (readfirstlane);
// x streams through a 20-row float4 register sliding window (17x reuse in
// regs); one group (4 rows) prefetched ahead. Edge rows use per-m weights
// from the banded pmb table (wave-uniform branch, 2 of 16 groups).

#define N_TOK 256
#define C_CH  128
#define NV    32              // c/4 float4 columns
#define HW    8               // band half-width (exp(-0.475 d^2): |d|>8 < 3e-18)
#define TAPS  17
#define PMPAD 18              // padded taps per m in ws table
#define SEG   64              // m rows per wave
#define GS    4               // rows per group (sliding-window step)
#define NG    (SEG / GS)      // 16 groups
#define WROWS (GS + 2 * HW)   // 20 window rows

// ---------------- kernel 1: banded posmap table (256 x 18 float4) -----------
// pmb[m][d] (d = n-m+8, 0..16; 17 zero). Invalid n -> 0 weight. Row 128 is the
// interior stencil.
__global__ void pm_build_kernel(const float* __restrict__ centers,
                                const float* __restrict__ spreads,
                                float* __restrict__ pmb) {
    const int m    = blockIdx.x;       // 0..255
    const int lane = threadIdx.x;      // 0..63
    const int n    = m + lane - HW;
    const bool valid = (lane < TAPS) && ((unsigned)n < N_TOK);
    const float dd = (float)(lane - HW);

    float e[4];
#pragma unroll
    for (int s = 0; s < 4; ++s) {
        const float ctr = centers[s];
        const float spr = spreads[s];
        const float sc = (ctr * spr) * dd - 0.5f * spr * dd * dd;
        e[s] = valid ? expf(sc) : 0.0f;
    }
#pragma unroll
    for (int s = 0; s < 4; ++s) {
        float v = e[s];
#pragma unroll
        for (int off = 32; off; off >>= 1) v += __shfl_xor(v, off, 64);
        e[s] = e[s] / __shfl(v, 0, 64);   // 0 for invalid lanes
    }
    if (lane < PMPAD) {
        reinterpret_cast<float4*>(pmb)[m * PMPAD + lane] =
            make_float4(e[0], e[1], e[2], e[3]);
    }
}

// ---------------- kernel 2: register-window 17-tap conv ---------------------
// block: 256 thr = 4 waves = 4 m-segments x (2 images x 32 cols).
// grid: 1024 image-pairs. Segment halos of the same images share the CU's L1.
__global__ __launch_bounds__(256, 4)
void pm_apply_kernel(const float* __restrict__ x,
                     const float* __restrict__ pmb,
                     const float* __restrict__ bias,
                     float* __restrict__ out) {
    const int tid  = threadIdx.x;
    const int wave = tid >> 6;          // 0..3 = m segment
    const int lane = tid & 63;
    const int imgl = lane >> 5;         // 0..1
    const int col  = lane & 31;
    const int img  = (blockIdx.x << 1) | imgl;
    const int m0   = wave * SEG;

    const float4* xb = reinterpret_cast<const float4*>(x)
                       + (size_t)img * (N_TOK * NV) + col;
    float4*       ob = reinterpret_cast<float4*>(out)
                       + (size_t)img * (N_TOK * NV) + col;
    // row n lives at xb[n * NV]

    // interior stencil (pmb row 128) -> SGPRs via readfirstlane
    float wsc[TAPS * 4];
    {
        const float* wrow = pmb + 128 * (PMPAD * 4);
#pragma unroll
        for (int t = 0; t < TAPS * 4; ++t)
            wsc[t] = __int_as_float(
                __builtin_amdgcn_readfirstlane(__float_as_int(wrow[t])));
    }

    // initial window: rows m0-8 .. m0+11 (clamp low; weights 0 there)
    float4 R[WROWS];
#pragma unroll
    for (int i = 0; i < WROWS; ++i) {
        int r = m0 - HW + i;
        r = r < 0 ? 0 : r;
        R[i] = xb[r * NV];
    }
    float4 Nx[GS];

#pragma unroll 1
    for (int g = 0; g < NG; ++g) {
        const int mb = m0 + g * GS;

        // prefetch next group's 4 incoming rows (hidden under this group's FMAs)
        if (g < NG - 1) {
#pragma unroll
            for (int i = 0; i < GS; ++i) {
                int r = mb + GS + HW + i;          // mb+12 .. mb+15
                r = r > N_TOK - 1 ? N_TOK - 1 : r; // clamped rows have 0 weight
                Nx[i] = xb[r * NV];
            }
        }

        const bool edge = (m0 == 0 && g < 2) || (m0 == 192 && g >= NG - 2);
        if (!edge) {
#pragma unroll
            for (int j = 0; j < GS; ++j) {
                const int m = mb + j;
                const float bv = bias[m];
                float ax = bv, ay = bv, az = bv, aw = bv;
#pragma unroll
                for (int t = 0; t < TAPS; ++t) {
                    const float4 xv = R[j + t];
                    ax += wsc[t * 4 + 0] * xv.x;
                    ay += wsc[t * 4 + 1] * xv.y;
                    az += wsc[t * 4 + 2] * xv.z;
                    aw += wsc[t * 4 + 3] * xv.w;
                }
                ob[m * NV] = make_float4(ax, ay, az, aw);
            }
        } else {
            // 16 edge rows total: per-m renormalized weights from pmb (L2 broadcast)
#pragma unroll
            for (int j = 0; j < GS; ++j) {
                const int m = mb + j;
                const float bv = bias[m];
                float ax = bv, ay = bv, az = bv, aw = bv;
                const float4* pmrow = reinterpret_cast<const float4*>(pmb) + m * PMPAD;
#pragma unroll
                for (int t = 0; t < TAPS; ++t) {
                    const float4 w  = pmrow[t];
                    const float4 xv = R[j + t];
                    ax += w.x * xv.x;
                    ay += w.y * xv.y;
                    az += w.z * xv.z;
                    aw += w.w * xv.w;
                }
                ob[m * NV] = make_float4(ax, ay, az, aw);
            }
        }

        // slide window by GS
#pragma unroll
        for (int i = 0; i < WROWS - GS; ++i) R[i] = R[i + GS];
#pragma unroll
        for (int i = 0; i < GS; ++i) R[WROWS - GS + i] = Nx[i];
    }
}

extern "C" void kernel_launch(void* const* d_in, const int* in_sizes, int n_in,
                              void* d_out, int out_size, void* d_ws, size_t ws_size,
                              hipStream_t stream) {
    const float* x       = (const float*)d_in[0];  // (16,128,256,128)
    const float* centers = (const float*)d_in[1];  // (4,1)
    const float* spreads = (const float*)d_in[2];  // (4,1)
    const float* bias    = (const float*)d_in[3];  // (1,256,1)
    float* out = (float*)d_out;
    float* pmb = (float*)d_ws;                     // 256*18 float4 = 73.7 KB

    pm_build_kernel<<<dim3(N_TOK), dim3(64), 0, stream>>>(centers, spreads, pmb);

    const int n_imgpair = (16 * 128) / 2;          // 1024
    pm_apply_kernel<<<dim3(n_imgpair), dim3(256), 0, stream>>>(
        x, pmb, bias, out);
}